// Round 1
// baseline (630.800 us; speedup 1.0000x reference)
//
#include <hip/hip_runtime.h>

#define N_SUBJ 4096
#define N_STEPS 2048
#define N_DOSES 8

__device__ __forceinline__ float softplusf(float x) {
    // jax.nn.softplus(x) = max(x,0) + log1p(exp(-|x|))
    return fmaxf(x, 0.0f) + log1pf(expf(-fabsf(x)));
}

__global__ __launch_bounds__(64) void pkpd_rk4_kernel(
    const float* __restrict__ cov,       // (N,2)
    const float* __restrict__ dose_int,  // (N,)
    const float* __restrict__ W,         // (3,9)
    const float* __restrict__ b,         // (9,)
    const float* __restrict__ dose_amt,  // (N,8)
    float* __restrict__ out)             // (N, N_STEPS+1, 4)
{
    const int i = blockIdx.x * blockDim.x + threadIdx.x;
    if (i >= N_SUBJ) return;

    // ---- parameter network: params = softplus(feats @ W + b) + 0.01 ----
    const float f0 = cov[2 * i] * 0.01f;
    const float f1 = cov[2 * i + 1];
    const float f2 = dose_int[i];

    float P[9];
#pragma unroll
    for (int p = 0; p < 9; ++p) {
        float z = f0 * W[p] + f1 * W[9 + p] + f2 * W[18 + p] + b[p];
        P[p] = softplusf(z) + 0.01f;
    }
    const float Ka = P[0], CL = P[1], Vc = P[2], Q = P[3], Vp = P[4];
    const float Kin = P[5], Kout = P[6], Imax = P[7], IC50 = P[8];

    // per-subject rate constants (hoisted divisions)
    const float k10   = CL / Vc;
    const float k12   = Q / Vc;
    const float k21   = Q / Vp;
    const float invVc = 1.0f / Vc;

    const float dt = 504.0f / (float)N_STEPS;   // 0.24609375
    const float half_dt = 0.5f * dt;
    const float dt6 = dt / 6.0f;

    float doses[N_DOSES];
#pragma unroll
    for (int d = 0; d < N_DOSES; ++d) doses[d] = dose_amt[i * N_DOSES + d];

    float Ad = 0.0f, Ac = 0.0f, Ap = 0.0f, R = 16.0f;

    float4* orow = (float4*)(out + (size_t)i * (size_t)(N_STEPS + 1) * 4);
    orow[0] = make_float4(0.0f, 0.0f, 0.0f, 16.0f);

    const int steps_per_dose = N_STEPS / N_DOSES;  // 256

#define RHS(ad, ac, ap, r, dad, dac, dap, dr)                         \
    do {                                                              \
        dad = -Ka * (ad);                                             \
        dac = Ka * (ad) - k10 * (ac) - k12 * (ac) + k21 * (ap);       \
        dap = k12 * (ac) - k21 * (ap);                                \
        float conc_ = (ac) * invVc;                                   \
        float inh_ = Imax * conc_ / (IC50 + conc_ + 1e-6f);           \
        dr = Kin * (1.0f - inh_) - Kout * (r);                        \
    } while (0)

    for (int t = 0; t < N_STEPS; ++t) {
        if ((t & (steps_per_dose - 1)) == 0) Ad += doses[t / steps_per_dose];

        float k1a, k1c, k1p, k1r;
        RHS(Ad, Ac, Ap, R, k1a, k1c, k1p, k1r);

        float y2a = Ad + half_dt * k1a, y2c = Ac + half_dt * k1c;
        float y2p = Ap + half_dt * k1p, y2r = R + half_dt * k1r;
        float k2a, k2c, k2p, k2r;
        RHS(y2a, y2c, y2p, y2r, k2a, k2c, k2p, k2r);

        float y3a = Ad + half_dt * k2a, y3c = Ac + half_dt * k2c;
        float y3p = Ap + half_dt * k2p, y3r = R + half_dt * k2r;
        float k3a, k3c, k3p, k3r;
        RHS(y3a, y3c, y3p, y3r, k3a, k3c, k3p, k3r);

        float y4a = Ad + dt * k3a, y4c = Ac + dt * k3c;
        float y4p = Ap + dt * k3p, y4r = R + dt * k3r;
        float k4a, k4c, k4p, k4r;
        RHS(y4a, y4c, y4p, y4r, k4a, k4c, k4p, k4r);

        Ad = Ad + dt6 * (k1a + 2.0f * k2a + 2.0f * k3a + k4a);
        Ac = Ac + dt6 * (k1c + 2.0f * k2c + 2.0f * k3c + k4c);
        Ap = Ap + dt6 * (k1p + 2.0f * k2p + 2.0f * k3p + k4p);
        R  = R  + dt6 * (k1r + 2.0f * k2r + 2.0f * k3r + k4r);

        orow[t + 1] = make_float4(Ad, Ac, Ap, R);
    }
#undef RHS
}

extern "C" void kernel_launch(void* const* d_in, const int* in_sizes, int n_in,
                              void* d_out, int out_size, void* d_ws, size_t ws_size,
                              hipStream_t stream) {
    const float* cov      = (const float*)d_in[0];
    const float* dose_int = (const float*)d_in[1];
    const float* W        = (const float*)d_in[2];
    const float* b        = (const float*)d_in[3];
    const float* dose_amt = (const float*)d_in[4];
    float* out = (float*)d_out;

    dim3 block(64);
    dim3 grid((N_SUBJ + 63) / 64);
    pkpd_rk4_kernel<<<grid, block, 0, stream>>>(cov, dose_int, W, b, dose_amt, out);
}

// Round 2
// 104.036 us; speedup vs baseline: 6.0633x; 6.0633x over previous
//
#include <hip/hip_runtime.h>

#define N_SUBJ 4096
#define N_STEPS 2048
#define N_DOSES 8
#define NCH 64          // chunks per subject (= one wave lane per chunk)
#define CLEN 32         // steps per chunk; dose steps (multiples of 256) are chunk starts
#define PSTRIDE 16

#define DT   0.24609375f          // 504/2048, exact
#define HH   0.123046875f         // dt/2, exact
#define DT6  0.041015625f         // dt/6, exact

__device__ __forceinline__ float softplusf(float x) {
    return fmaxf(x, 0.0f) + log1pf(expf(-fabsf(x)));
}

__device__ __forceinline__ void mm3(float* C, const float* A, const float* B) {
#pragma unroll
    for (int i = 0; i < 3; ++i)
#pragma unroll
        for (int j = 0; j < 3; ++j)
            C[3 * i + j] = A[3 * i] * B[j] + A[3 * i + 1] * B[3 + j] + A[3 * i + 2] * B[6 + j];
}

// ---------------- K1: params, derived constants, Phi^32, chunk-start PK scan ---------
__global__ __launch_bounds__(256) void k1_setup(
    const float* __restrict__ cov, const float* __restrict__ dose_int,
    const float* __restrict__ W, const float* __restrict__ b,
    const float* __restrict__ dose_amt,
    float* __restrict__ par, float* __restrict__ ypre)
{
    const int i = blockIdx.x * 256 + threadIdx.x;
    if (i >= N_SUBJ) return;

    const float f0 = cov[2 * i] * 0.01f;
    const float f1 = cov[2 * i + 1];
    const float f2 = dose_int[i];

    float P[9];
#pragma unroll
    for (int p = 0; p < 9; ++p) {
        float z = f0 * W[p] + f1 * W[9 + p] + f2 * W[18 + p] + b[p];
        P[p] = softplusf(z) + 0.01f;
    }
    const float Ka = P[0], CL = P[1], Vc = P[2], Q = P[3], Vp = P[4];
    const float Kin = P[5], Kout = P[6], Imax = P[7], IC50 = P[8];

    const float k10 = CL / Vc, k12 = Q / Vc, k21 = Q / Vp, invVc = 1.0f / Vc;

    // R recurrence: R' = alpha*R + beta,  beta = beta0 - sum w_i * inh_i
    const float x = DT * Kout;
    const float x2 = x * x;
    const float alpha = 1.0f - x + 0.5f * x2 - (1.0f / 6.0f) * x2 * x + (1.0f / 24.0f) * x2 * x2;
    const float a = 0.5f * x;
    const float g1 = 1.0f - 2.0f * a + 2.0f * a * a - 2.0f * a * a * a;
    const float g2 = 2.0f - 2.0f * a + 2.0f * a * a;
    const float g3 = 2.0f - 2.0f * a;
    const float s = DT * Kin * (1.0f / 6.0f);
    const float w1 = s * g1, w2 = s * g2, w3 = s * g3, w4 = s;
    const float beta0 = w1 + w2 + w3 + w4;

    float* pp = par + i * PSTRIDE;
    pp[0] = Ka; pp[1] = k10; pp[2] = k12; pp[3] = k21; pp[4] = invVc;
    pp[5] = Imax; pp[6] = IC50 + 1e-6f; pp[7] = alpha; pp[8] = beta0;
    pp[9] = w1; pp[10] = w2; pp[11] = w3; pp[12] = w4;

    // Phi = RK4 one-step map of the linear PK system; M = Phi^CLEN
    float A[9] = { -DT * Ka, 0.0f, 0.0f,
                    DT * Ka, -DT * (k10 + k12), DT * k21,
                    0.0f, DT * k12, -DT * k21 };
    float T2[9], T3[9], T4[9], M[9], Tmp[9];
    mm3(T2, A, A); mm3(T3, T2, A); mm3(T4, T3, A);
#pragma unroll
    for (int e = 0; e < 9; ++e)
        M[e] = A[e] + 0.5f * T2[e] + (1.0f / 6.0f) * T3[e] + (1.0f / 24.0f) * T4[e];
    M[0] += 1.0f; M[4] += 1.0f; M[8] += 1.0f;
#pragma unroll
    for (int sq = 0; sq < 5; ++sq) {   // Phi^2,4,8,16,32
        mm3(Tmp, M, M);
#pragma unroll
        for (int e = 0; e < 9; ++e) M[e] = Tmp[e];
    }

    // scan chunk-start (pre-dose) PK states
    float ya = 0.0f, yb = 0.0f, yc = 0.0f;
    float* yo = ypre + (size_t)i * NCH * 3;
    for (int c = 0; c < NCH; ++c) {
        yo[3 * c] = ya; yo[3 * c + 1] = yb; yo[3 * c + 2] = yc;
        if ((c & 7) == 0) ya += dose_amt[i * N_DOSES + (c >> 3)];
        float na = M[0] * ya + M[1] * yb + M[2] * yc;
        float nb = M[3] * ya + M[4] * yb + M[5] * yc;
        float nc2 = M[6] * ya + M[7] * yb + M[8] * yc;
        ya = na; yb = nb; yc = nc2;
    }
}

// ---------------- K3: per-subject R scan over chunk summaries ------------------------
__global__ __launch_bounds__(256) void k3_rscan(
    const float* __restrict__ par, const float* __restrict__ Bsum,
    float* __restrict__ Rst)
{
    const int i = blockIdx.x * 256 + threadIdx.x;
    if (i >= N_SUBJ) return;
    float alpha = par[i * PSTRIDE + 7];
    float a32 = alpha;
#pragma unroll
    for (int sq = 0; sq < 5; ++sq) a32 = a32 * a32;   // alpha^32
    float R = 16.0f;
    const float* Bp = Bsum + i * NCH;
    float* Rp = Rst + i * NCH;
    for (int c = 0; c < NCH; ++c) {
        Rp[c] = R;
        R = a32 * R + Bp[c];
    }
}

// ---------------- K2 / K4: per-chunk RK4 stepping ------------------------------------
template <bool FINAL>
__global__ __launch_bounds__(256) void chunk_kernel(
    const float* __restrict__ par, const float* __restrict__ ypre,
    const float* __restrict__ dose_amt,
    float* __restrict__ Bsum, const float* __restrict__ Rst,
    float* __restrict__ out)
{
    const int subj = blockIdx.x * 4 + (threadIdx.x >> 6);
    const int c = threadIdx.x & 63;

    const float* pp = par + subj * PSTRIDE;
    const float Ka = pp[0], k10 = pp[1], k12 = pp[2], k21 = pp[3], invVc = pp[4];
    const float Imax = pp[5], IC50p = pp[6], alpha = pp[7], beta0 = pp[8];
    const float w1 = pp[9], w2 = pp[10], w3 = pp[11], w4 = pp[12];

    const float* yp = ypre + (size_t)(subj * NCH + c) * 3;
    float Ad = yp[0], Ac = yp[1], Ap = yp[2];
    if ((c & 7) == 0) Ad += dose_amt[subj * N_DOSES + (c >> 3)];

    float R = 0.0f, B = 0.0f;
    float4* orow = nullptr;
    if (FINAL) {
        R = Rst[subj * NCH + c];
        orow = (float4*)out + (size_t)subj * (N_STEPS + 1);
        if (c == 0) orow[0] = make_float4(0.0f, 0.0f, 0.0f, 16.0f);
    }

    for (int j = 0; j < CLEN; ++j) {
        float k1a = -Ka * Ad;
        float k1c = Ka * Ad - k10 * Ac - k12 * Ac + k21 * Ap;
        float k1p = k12 * Ac - k21 * Ap;
        float y2a = Ad + HH * k1a, y2c = Ac + HH * k1c, y2p = Ap + HH * k1p;
        float k2a = -Ka * y2a;
        float k2c = Ka * y2a - k10 * y2c - k12 * y2c + k21 * y2p;
        float k2p = k12 * y2c - k21 * y2p;
        float y3a = Ad + HH * k2a, y3c = Ac + HH * k2c, y3p = Ap + HH * k2p;
        float k3a = -Ka * y3a;
        float k3c = Ka * y3a - k10 * y3c - k12 * y3c + k21 * y3p;
        float k3p = k12 * y3c - k21 * y3p;
        float y4a = Ad + DT * k3a, y4c = Ac + DT * k3c, y4p = Ap + DT * k3p;
        float k4a = -Ka * y4a;
        float k4c = Ka * y4a - k10 * y4c - k12 * y4c + k21 * y4p;
        float k4p = k12 * y4c - k21 * y4p;

        // inhibition at the 4 stage A_c values -> beta_n
        float conc1 = Ac * invVc, conc2 = y2c * invVc;
        float conc3 = y3c * invVc, conc4 = y4c * invVc;
        float inh1 = __fdividef(Imax * conc1, IC50p + conc1);
        float inh2 = __fdividef(Imax * conc2, IC50p + conc2);
        float inh3 = __fdividef(Imax * conc3, IC50p + conc3);
        float inh4 = __fdividef(Imax * conc4, IC50p + conc4);
        float beta = beta0 - w1 * inh1 - w2 * inh2 - w3 * inh3 - w4 * inh4;

        if (FINAL) R = alpha * R + beta;
        else       B = alpha * B + beta;

        Ad = Ad + DT6 * (k1a + 2.0f * k2a + 2.0f * k3a + k4a);
        Ac = Ac + DT6 * (k1c + 2.0f * k2c + 2.0f * k3c + k4c);
        Ap = Ap + DT6 * (k1p + 2.0f * k2p + 2.0f * k3p + k4p);

        if (FINAL) orow[c * CLEN + j + 1] = make_float4(Ad, Ac, Ap, R);
    }

    if (!FINAL) Bsum[subj * NCH + c] = B;
}

extern "C" void kernel_launch(void* const* d_in, const int* in_sizes, int n_in,
                              void* d_out, int out_size, void* d_ws, size_t ws_size,
                              hipStream_t stream) {
    const float* cov      = (const float*)d_in[0];
    const float* dose_int = (const float*)d_in[1];
    const float* W        = (const float*)d_in[2];
    const float* b        = (const float*)d_in[3];
    const float* dose_amt = (const float*)d_in[4];
    float* out = (float*)d_out;

    float* par  = (float*)d_ws;                    // [N_SUBJ][PSTRIDE]
    float* ypre = par + (size_t)N_SUBJ * PSTRIDE;  // [N_SUBJ][NCH][3]
    float* Bsum = ypre + (size_t)N_SUBJ * NCH * 3; // [N_SUBJ][NCH]
    float* Rst  = Bsum + (size_t)N_SUBJ * NCH;     // [N_SUBJ][NCH]

    k1_setup<<<N_SUBJ / 256, 256, 0, stream>>>(cov, dose_int, W, b, dose_amt, par, ypre);
    chunk_kernel<false><<<N_SUBJ / 4, 256, 0, stream>>>(par, ypre, dose_amt, Bsum, Rst, out);
    k3_rscan<<<N_SUBJ / 256, 256, 0, stream>>>(par, Bsum, Rst);
    chunk_kernel<true><<<N_SUBJ / 4, 256, 0, stream>>>(par, ypre, dose_amt, Bsum, Rst, out);
}